// Round 18
// baseline (167.134 us; speedup 1.0000x reference)
//
#include <hip/hip_runtime.h>
#include <stdint.h>

// VanillaRNN fused: B=2048,S=125,I=2,H=300,O=2
// h_t = relu(x_t@W_ih^T + b_ih + h_{t-1}@W_hh^T + b_hh) + 0.01*noise_t
// out = h_t @ W_out^T + b_out
//
// R18: 8 waves x 3 tiles (T=3) at 2 waves/SIMD.
//  - A-frag LDS reads = 10 x (compute waves): 10 waves spent ~1200cy/step;
//    7 compute waves spend ~840. Wave 7 = DMA/barrier only.
//  - Register-split model (R9/R13/R15 evidence: reported VGPR = arch half
//    of 512/waves_per_eu): wf must fit the AGPR half. T=3 -> wf=120 <= 128
//    (2 waves/SIMD); arch side (10 h-frags + 6 acc chains + temps ~100)
//    <= 128. T=4 (R9) violated this (160 > 128) and spilled.
//  - cols = w*48 + t*16 + (grp*4 + r); 21 tiles cover the 304-col padded
//    space; W_out cols 300/301 = wave 6, tile 0, grp 3. Waves run all 3
//    tiles uniformly (wave 6 t1/t2 have zero wf) -> 60 MFMA issue/SIMD,
//    balanced, no MFMA-path branches.
//  - noise DMA: wave w owns 75 chunks (2 instrs/step: 64 + 11 masked) ->
//    uniform counted barrier vmcnt(2). Transposed SOURCE swizzle kept:
//    slot s holds chunk(row=s&7, cc=s>>3) -> epilogue float4 reads are
//    conflict-free ((12w+4t+g)*32 + lc*4; 32 lanes, 32 banksets).
//  - carried: swapped MFMA (A=W regs, B=h LDS), x/bias K-rows 300-302,
//    zero-row Abuf, 3-buf Nbuf 2 ahead, single-asm barrier, 6-period
//    unroll, named h-frag preload. NO setprio (R16 spill).

#define SEQ   125
#define HID   300
#define APAD  328     // Abuf row stride in shorts
#define KT    10
#define WAVES 8
#define NTH   (WAVES * 64)
#define RPW   8
#define NSLAB 2400    // floats per Nbuf slab (75 chunks x 8 waves x 4)

typedef __attribute__((ext_vector_type(8))) short bf16x8;
typedef __attribute__((ext_vector_type(4))) float f32x4;

__device__ __forceinline__ short f2bf(float f) {
  union { float f; uint32_t u; } v; v.f = f;
  uint32_t r = (v.u + 0x7fffu + ((v.u >> 16) & 1u)) >> 16;  // RNE
  return (short)r;
}

__device__ __forceinline__ uint32_t cvt_pk_bf16(float lo, float hi) {
  uint32_t r;
  asm("v_cvt_pk_bf16_f32 %0, %1, %2" : "=v"(r) : "v"(lo), "v"(hi));
  return r;
}

__device__ __forceinline__ void dma16(const float* g, float* l) {
  __builtin_amdgcn_global_load_lds(
      (const __attribute__((address_space(1))) unsigned int*)g,
      (__attribute__((address_space(3))) unsigned int*)l, 16, 0, 0);
}

// Every wave issues exactly 2 DMA instrs/step. At the barrier the two
// oldest (next step's slab) must have retired -> vmcnt(2): the 2 newest
// (slab s+2) stay in flight across the barrier. Single asm block.
#define STEP_BARRIER() \
  asm volatile("s_waitcnt vmcnt(2) lgkmcnt(0)\n\ts_barrier" ::: "memory")

__global__ __launch_bounds__(NTH)
__attribute__((amdgpu_waves_per_eu(2, 2)))
void rnn_fused(
    const float* __restrict__ x,      // [2048,125,2]
    const float* __restrict__ noise,  // [2048,125,300]
    const float* __restrict__ W_ih,   // [300,2]
    const float* __restrict__ b_ih,   // [300]
    const float* __restrict__ W_hh,   // [300,300]
    const float* __restrict__ b_hh,   // [300]
    const float* __restrict__ W_out,  // [2,300]
    const float* __restrict__ b_out,  // [2]
    float* __restrict__ out)          // [2048,125,2]
{
  // rows 0..7 = batch rows' h (+x cols 300-301, bias col 302); row 8 = zeros
  __shared__ __align__(16) short Abuf[2][9][APAD];   // 11808 B
  __shared__ __align__(16) float Nbuf[3][NSLAB];     // 28800 B noise 3-buf
  __shared__ float xbuf[RPW][SEQ * 2];               //  8000 B
  __shared__ float outbuf[RPW][SEQ * 2];             //  8000 B

  const int tid  = threadIdx.x;
  const int wave = tid >> 6;
  const int lane = tid & 63;
  const int grp  = lane >> 4;     // 0..3
  const int lc   = lane & 15;     // 0..15
  const int row0 = blockIdx.x * RPW;
  const int grp8 = grp * 8;
  const int arow = (lc < 8) ? lc : 8;     // zero-row broadcast
  const bool lcr = (lc < 8);              // lane's batch row is real
  const int cb0  = wave * 48 + grp * 4;   // tile0 output-col base
  // conflict-free Nbuf read base: slot(row=lc, cc=12w+4t+g) -> float idx
  const int nrd0 = (12 * wave + grp) * 32 + lc * 4;   // + t*128

  // zero both Abuf buffers (incl. zero-row + cols 303..327)
  for (int i = tid; i < 2 * 9 * APAD / 2; i += NTH)
    ((uint32_t*)Abuf)[i] = 0u;
  // stage x
  for (int i = tid; i < RPW * SEQ * 2; i += NTH) {
    int r = i / (SEQ * 2), j = i % (SEQ * 2);
    xbuf[r][j] = x[(row0 + r) * (SEQ * 2) + j];
  }

  const float bout0 = b_out[0], bout1 = b_out[1];

  // ---- persistent A-side fragments: wf[t][kt], lane holds W for col
  // c = wave*48 + t*16 + lc, k = kt*32 + grp*8 + e.
  // k=300/301: W_ih; k=302: b_ih+b_hh; c=300/301: W_out rows (k<300).
  // Waves 6 (t>=1) and 7: c >= 304 -> all-zero frags (harmless MFMAs).
  bf16x8 wf[3][KT];
#pragma unroll
  for (int t = 0; t < 3; ++t) {
    int c = wave * 48 + t * 16 + lc;
#pragma unroll
    for (int kt = 0; kt < KT; ++kt) {
      bf16x8 f;
#pragma unroll
      for (int e = 0; e < 8; ++e) {
        int k = kt * 32 + grp8 + e;
        float v = 0.f;
        if (c < HID) {
          if (k < HID)            v = W_hh[c * HID + k];
          else if (k == HID)      v = W_ih[c * 2 + 0];
          else if (k == HID + 1)  v = W_ih[c * 2 + 1];
          else if (k == HID + 2)  v = b_ih[c] + b_hh[c];
        } else if (c == HID) {
          if (k < HID)            v = W_out[k];
        } else if (c == HID + 1) {
          if (k < HID)            v = W_out[HID + k];
        }
        f[e] = f2bf(v);
      }
      wf[t][kt] = f;
    }
  }

  // ---- noise DMA: wave owns chunks [75w, 75w+75). slot s holds chunk
  // (row = s&7, cc = s>>3); source permuted, dest wave-linear.
  const int s1 = wave * 75 + lane;               // instr1 (all lanes)
  const int s2 = wave * 75 + 64 + ((lane < 11) ? lane : 10);  // instr2
  const float* g1 = noise + (size_t)(row0 + (s1 & 7)) * (SEQ * HID) + ((s1 >> 3) << 2);
  const float* g2 = noise + (size_t)(row0 + (s2 & 7)) * (SEQ * HID) + ((s2 >> 3) << 2);

  __syncthreads();  // Abuf zeros + xbuf visible

  // post-zero init: x_0 into Abuf[0] cols 300-301; bias-one col 302 (both)
  if (tid < 8) {
    float2 xv = *(const float2*)&x[(size_t)(row0 + tid) * (SEQ * 2)];
    *(uint32_t*)&Abuf[0][tid][300] = cvt_pk_bf16(xv.x, xv.y);
    Abuf[0][tid][302] = (short)0x3F80;   // bf16 1.0
    Abuf[1][tid][302] = (short)0x3F80;
  }

  // prologue DMA: slabs 0 and 1 (4 instrs/wave -> vmcnt(2) = slab 0 landed)
  dma16(g1, &Nbuf[0][wave * 300]);
  if (lane < 11) dma16(g2, &Nbuf[0][wave * 300 + 256]);
  dma16(g1 + HID, &Nbuf[1][wave * 300]);
  if (lane < 11) dma16(g2 + HID, &Nbuf[1][wave * 300 + 256]);
  int gofs = 2 * HID;
  STEP_BARRIER();  // slab 0 landed; slab 1 in flight; init LDS visible

  const bool xw = (wave == 0) && (grp == 0) && lcr;  // lanes 0-7

  // one MFMA "row" pair: even kt -> a-chains, odd kt -> b-chains
#define MM2(KE, HE, KO, HO)                                                    \
    a0a = __builtin_amdgcn_mfma_f32_16x16x32_bf16(wf[0][KE], HE, a0a, 0,0,0);  \
    a1a = __builtin_amdgcn_mfma_f32_16x16x32_bf16(wf[1][KE], HE, a1a, 0,0,0);  \
    a2a = __builtin_amdgcn_mfma_f32_16x16x32_bf16(wf[2][KE], HE, a2a, 0,0,0);  \
    a0b = __builtin_amdgcn_mfma_f32_16x16x32_bf16(wf[0][KO], HO, a0b, 0,0,0);  \
    a1b = __builtin_amdgcn_mfma_f32_16x16x32_bf16(wf[1][KO], HO, a1b, 0,0,0);  \
    a2b = __builtin_amdgcn_mfma_f32_16x16x32_bf16(wf[2][KO], HO, a2b, 0,0,0);

  // Iteration S: MFMA on Abuf[CUR] (= h_{S-1} + x_S + bias); out[S-1]
  // from cols 300/301 (S>=1, wave6/grp3); epilogue writes h_S + x_{S+1}.
#define STEPM(S, CUR, RB, WB, DO_OUT, DO_EPI, DO_X, DO_ADV, DO_DMA)            \
  {                                                                            \
    if (DO_DMA) {                                                              \
      dma16(g1 + gofs, &Nbuf[WB][wave * 300]);                                 \
      if (lane < 11) dma16(g2 + gofs, &Nbuf[WB][wave * 300 + 256]);            \
    }                                                                          \
    if (DO_ADV) gofs += HID;                                                   \
    if (wave != 7) {                                                           \
      const short* Ab = &Abuf[CUR][arow][grp8];                                \
      bf16x8 h0 = *(const bf16x8*)(Ab + 0);                                    \
      bf16x8 h1 = *(const bf16x8*)(Ab + 32);                                   \
      bf16x8 h2 = *(const bf16x8*)(Ab + 64);                                   \
      bf16x8 h3 = *(const bf16x8*)(Ab + 96);                                   \
      bf16x8 h4 = *(const bf16x8*)(Ab + 128);                                  \
      bf16x8 h5 = *(const bf16x8*)(Ab + 160);                                  \
      bf16x8 h6 = *(const bf16x8*)(Ab + 192);                                  \
      bf16x8 h7 = *(const bf16x8*)(Ab + 224);                                  \
      bf16x8 h8 = *(const bf16x8*)(Ab + 256);                                  \
      bf16x8 h9 = *(const bf16x8*)(Ab + 288);                                  \
      f32x4 a0a = {0.f,0.f,0.f,0.f}, a0b = {0.f,0.f,0.f,0.f};                  \
      f32x4 a1a = {0.f,0.f,0.f,0.f}, a1b = {0.f,0.f,0.f,0.f};                  \
      f32x4 a2a = {0.f,0.f,0.f,0.f}, a2b = {0.f,0.f,0.f,0.f};                  \
      MM2(0, h0, 1, h1)                                                        \
      MM2(2, h2, 3, h3)                                                        \
      MM2(4, h4, 5, h5)                                                        \
      MM2(6, h6, 7, h7)                                                        \
      MM2(8, h8, 9, h9)                                                        \
      f32x4 ac0 = a0a + a0b, ac1 = a1a + a1b, ac2 = a2a + a2b;                 \
      if (wave < 6) {                                                          \
        if (DO_EPI) { if (lcr) {                                               \
          float4 n0 = *(const float4*)&Nbuf[RB][nrd0];                         \
          float4 n1 = *(const float4*)&Nbuf[RB][nrd0 + 128];                   \
          float4 n2 = *(const float4*)&Nbuf[RB][nrd0 + 256];                   \
          float v0 = fmaxf(ac0[0], 0.f) + 0.01f * n0.x;                        \
          float v1 = fmaxf(ac0[1], 0.f) + 0.01f * n0.y;                        \
          float v2 = fmaxf(ac0[2], 0.f) + 0.01f * n0.z;                        \
          float v3 = fmaxf(ac0[3], 0.f) + 0.01f * n0.w;                        \
          float w0 = fmaxf(ac1[0], 0.f) + 0.01f * n1.x;                        \
          float w1 = fmaxf(ac1[1], 0.f) + 0.01f * n1.y;                        \
          float w2 = fmaxf(ac1[2], 0.f) + 0.01f * n1.z;                        \
          float w3 = fmaxf(ac1[3], 0.f) + 0.01f * n1.w;                        \
          float u0 = fmaxf(ac2[0], 0.f) + 0.01f * n2.x;                        \
          float u1 = fmaxf(ac2[1], 0.f) + 0.01f * n2.y;                        \
          float u2 = fmaxf(ac2[2], 0.f) + 0.01f * n2.z;                        \
          float u3 = fmaxf(ac2[3], 0.f) + 0.01f * n2.w;                        \
          uint2 p0; p0.x = cvt_pk_bf16(v0, v1); p0.y = cvt_pk_bf16(v2, v3);    \
          uint2 p1; p1.x = cvt_pk_bf16(w0, w1); p1.y = cvt_pk_bf16(w2, w3);    \
          uint2 p2; p2.x = cvt_pk_bf16(u0, u1); p2.y = cvt_pk_bf16(u2, u3);    \
          *(uint2*)&Abuf[(CUR) ^ 1][lc][cb0]      = p0;                        \
          *(uint2*)&Abuf[(CUR) ^ 1][lc][cb0 + 16] = p1;                        \
          *(uint2*)&Abuf[(CUR) ^ 1][lc][cb0 + 32] = p2;                        \
        } }                                                                    \
      } else { /* wave 6: tile 0 only (cols 288-303) */                        \
        if (DO_OUT) { if (grp == 3 && lcr) {                                   \
          float2 o; o.x = ac0[0] + bout0; o.y = ac0[1] + bout1;                \
          *(float2*)&outbuf[lc][((S) - 1) * 2] = o;                            \
        } }                                                                    \
        if (DO_EPI) { if (lcr && grp < 3) {                                    \
          float4 n0 = *(const float4*)&Nbuf[RB][nrd0];                         \
          float v0 = fmaxf(ac0[0], 0.f) + 0.01f * n0.x;                        \
          float v1 = fmaxf(ac0[1], 0.f) + 0.01f * n0.y;                        \
          float v2 = fmaxf(ac0[2], 0.f) + 0.01f * n0.z;                        \
          float v3 = fmaxf(ac0[3], 0.f) + 0.01f * n0.w;                        \
          uint2 p0; p0.x = cvt_pk_bf16(v0, v1); p0.y = cvt_pk_bf16(v2, v3);    \
          *(uint2*)&Abuf[(CUR) ^ 1][lc][cb0] = p0;                             \
        } }                                                                    \
      }                                                                        \
      if (DO_X) { if (xw) {                                                    \
        float2 xv = *(const float2*)&xbuf[lc][((S) + 1) * 2];                  \
        *(uint32_t*)&Abuf[(CUR) ^ 1][lc][300] = cvt_pk_bf16(xv.x, xv.y);       \
      } }                                                                      \
    }                                                                          \
    if (DO_EPI) STEP_BARRIER();                                                \
  }

  // peeled first block (S=0..5): no out-write at S=0
  STEPM(0, 0, 0, 2, 0, 1, 1, 1, 1);
  STEPM(1, 1, 1, 0, 1, 1, 1, 1, 1);
  STEPM(2, 0, 2, 1, 1, 1, 1, 1, 1);
  STEPM(3, 1, 0, 2, 1, 1, 1, 1, 1);
  STEPM(4, 0, 1, 0, 1, 1, 1, 1, 1);
  STEPM(5, 1, 2, 1, 1, 1, 1, 1, 1);

  // main: S = 6..119 (19 blocks of 6; all guards statically true)
  for (int s = 6; s < 120; s += 6) {
    STEPM(s + 0, 0, 0, 2, 1, 1, 1, 1, 1);
    STEPM(s + 1, 1, 1, 0, 1, 1, 1, 1, 1);
    STEPM(s + 2, 0, 2, 1, 1, 1, 1, 1, 1);
    STEPM(s + 3, 1, 0, 2, 1, 1, 1, 1, 1);
    STEPM(s + 4, 0, 1, 0, 1, 1, 1, 1, 1);
    STEPM(s + 5, 1, 2, 1, 1, 1, 1, 1, 1);
  }

  // tail S=120..125 (slab-124 re-issues keep per-wave vmcnt uniform)
  STEPM(120, 0, 0, 2, 1, 1, 1, 1, 1);
  STEPM(121, 1, 1, 0, 1, 1, 1, 1, 1);
  STEPM(122, 0, 2, 1, 1, 1, 1, 0, 1);  // issues slab 124; stop advancing
  STEPM(123, 1, 0, 2, 1, 1, 1, 0, 1);  // re-issue (dead buffer)
  STEPM(124, 0, 1, 0, 1, 1, 0, 0, 1);  // no x_125; re-issue (dead buffer)
  STEPM(125, 1, 2, 1, 1, 0, 0, 0, 0);  // MFMA + out[124] only, no barrier

#undef STEPM
#undef MM2

  __syncthreads();  // full drain; outbuf visible

  // coalesced flush
  for (int i = tid; i < RPW * SEQ * 2; i += NTH) {
    int r = i / (SEQ * 2), j = i % (SEQ * 2);
    out[(row0 + r) * (SEQ * 2) + j] = outbuf[r][j];
  }
}

extern "C" void kernel_launch(void* const* d_in, const int* in_sizes, int n_in,
                              void* d_out, int out_size, void* d_ws, size_t ws_size,
                              hipStream_t stream) {
  const float* xp     = (const float*)d_in[0];
  const float* noise  = (const float*)d_in[1];
  const float* W_ih   = (const float*)d_in[2];
  const float* b_ih   = (const float*)d_in[3];
  const float* W_hh   = (const float*)d_in[4];
  const float* b_hh   = (const float*)d_in[5];
  const float* W_out  = (const float*)d_in[6];
  const float* b_out  = (const float*)d_in[7];
  float* outp         = (float*)d_out;

  rnn_fused<<<dim3(2048 / RPW), dim3(NTH), 0, stream>>>(
      xp, noise, W_ih, b_ih, W_hh, b_hh, W_out, b_out, outp);
}

// Round 19
// 140.211 us; speedup vs baseline: 1.1920x; 1.1920x over previous
//
#include <hip/hip_runtime.h>
#include <stdint.h>

// VanillaRNN fused: B=2048,S=125,I=2,H=300,O=2
// h_t = relu(x_t@W_ih^T + b_ih + h_{t-1}@W_hh^T + b_hh) + 0.01*noise_t
// out = h_t @ W_out^T + b_out
//
// FINAL = R17 (best measured: 139.3us).
// Structure: 256 WGs x 640 threads (10 waves, 3 waves/SIMD pinned);
// each WG owns 8 batch rows for all 125 steps.
//  - swapped MFMA: A = W persistent in registers (wf 80 regs, lives in
//    the AGPR half of the unified file), B = h from LDS. C layout: lane
//    owns 1 batch row x 4 contiguous cols -> 2-op epilogue writes.
//  - x/bias folded as K-rows 300-302 of the h tile (W_ih/bias in wf).
//  - W_out rides as N-cols 300/301 -> out = free MFMA byproduct
//    (wave 9, grp 3); no cross-lane reduction anywhere.
//  - zero-row Abuf: B-frag lanes lc>=8 broadcast a shared zero row.
//  - noise: global_load_lds DMA, triple-buffered 2 steps ahead,
//    transposed-SOURCE swizzle (slot tid = chunk(row=tid&7, cc=tid>>3))
//    so epilogue float4 reads are conflict-free; dest stays wave-linear.
//  - single-asm counted barrier: s_waitcnt vmcnt(1) lgkmcnt(0); s_barrier
//    (newest DMA stays in flight across the barrier).
//  - 6-period fully-static step unroll (cur/rb/wb compile-time).
// Wave-count sweep (R15/R17/R18): 4w@1/SIMD=324us, 8w@2/SIMD=167us,
// 10w@3/SIMD=139us -> TLP dominates; this is the measured optimum.

#define SEQ   125
#define HID   300
#define APAD  328     // Abuf row stride in shorts
#define KT    10
#define WAVES 10
#define NTH   (WAVES * 64)
#define RPW   8
#define NCH   600     // 16B chunks per step-slab (8*300*4B/16)
#define NSLAB 2408    // floats per Nbuf slab (2400 + 8 pad)

typedef __attribute__((ext_vector_type(8))) short bf16x8;
typedef __attribute__((ext_vector_type(4))) float f32x4;

__device__ __forceinline__ short f2bf(float f) {
  union { float f; uint32_t u; } v; v.f = f;
  uint32_t r = (v.u + 0x7fffu + ((v.u >> 16) & 1u)) >> 16;  // RNE
  return (short)r;
}

__device__ __forceinline__ uint32_t cvt_pk_bf16(float lo, float hi) {
  uint32_t r;
  asm("v_cvt_pk_bf16_f32 %0, %1, %2" : "=v"(r) : "v"(lo), "v"(hi));
  return r;
}

__device__ __forceinline__ void dma16(const float* g, float* l) {
  __builtin_amdgcn_global_load_lds(
      (const __attribute__((address_space(1))) unsigned int*)g,
      (__attribute__((address_space(3))) unsigned int*)l, 16, 0, 0);
}

// Single-asm counted barrier: vmcnt(1) -> older of the 2 in-flight noise
// DMAs has landed; newer stays in flight across the barrier. lgkmcnt(0)
// -> own ds reads/writes done. One asm block = no hoisting window.
#define STEP_BARRIER() \
  asm volatile("s_waitcnt vmcnt(1) lgkmcnt(0)\n\ts_barrier" ::: "memory")

__global__ __launch_bounds__(NTH)
__attribute__((amdgpu_waves_per_eu(3, 3)))
void rnn_fused(
    const float* __restrict__ x,      // [2048,125,2]
    const float* __restrict__ noise,  // [2048,125,300]
    const float* __restrict__ W_ih,   // [300,2]
    const float* __restrict__ b_ih,   // [300]
    const float* __restrict__ W_hh,   // [300,300]
    const float* __restrict__ b_hh,   // [300]
    const float* __restrict__ W_out,  // [2,300]
    const float* __restrict__ b_out,  // [2]
    float* __restrict__ out)          // [2048,125,2]
{
  // rows 0..7 = batch rows' h (+x cols 300-301, bias col 302); row 8 = zeros
  __shared__ __align__(16) short Abuf[2][9][APAD];   // 11808 B
  __shared__ __align__(16) float Nbuf[3][NSLAB];     // 28896 B noise 3-buf
  __shared__ float xbuf[RPW][SEQ * 2];               //  8000 B
  __shared__ float outbuf[RPW][SEQ * 2];             //  8000 B

  const int tid  = threadIdx.x;
  const int wave = tid >> 6;
  const int lane = tid & 63;
  const int grp  = lane >> 4;     // 0..3
  const int lc   = lane & 15;     // 0..15
  const int row0 = blockIdx.x * RPW;
  const int grp8 = grp * 8;
  const int arow = (lc < 8) ? lc : 8;     // zero-row broadcast
  const bool lcr = (lc < 8);              // lane's batch row is real
  const bool w9  = (wave == 9);
  const int cb0  = wave * 32 + grp * 4;   // tile0 output-col base
  // transposed-swizzle Nbuf read: slot = 64w+8g+lc -> conflict-free
  const int nb0  = (wave * 64 + grp * 8 + lc) * 4;  // float index, tile0

  // zero both Abuf buffers (incl. zero-row + cols 302..327)
  for (int i = tid; i < 2 * 9 * APAD / 2; i += NTH)
    ((uint32_t*)Abuf)[i] = 0u;
  // stage x
  for (int i = tid; i < RPW * SEQ * 2; i += NTH) {
    int r = i / (SEQ * 2), j = i % (SEQ * 2);
    xbuf[r][j] = x[(row0 + r) * (SEQ * 2) + j];
  }

  const float bout0 = b_out[0], bout1 = b_out[1];

  // ---- persistent A-side fragments: wf[t][kt], lane holds W for col
  // c = wave*32 + t*16 + lc, k = kt*32 + grp*8 + e.
  // k=300/301: W_ih cols; k=302: b_ih+b_hh; c=300/301: W_out rows (k<300).
  bf16x8 wf0[KT], wf1[KT];
#pragma unroll
  for (int t = 0; t < 2; ++t) {
    int c = wave * 32 + t * 16 + lc;
#pragma unroll
    for (int kt = 0; kt < KT; ++kt) {
      bf16x8 f;
#pragma unroll
      for (int e = 0; e < 8; ++e) {
        int k = kt * 32 + grp8 + e;
        float v = 0.f;
        if (c < HID) {
          if (k < HID)            v = W_hh[c * HID + k];
          else if (k == HID)      v = W_ih[c * 2 + 0];
          else if (k == HID + 1)  v = W_ih[c * 2 + 1];
          else if (k == HID + 2)  v = b_ih[c] + b_hh[c];
        } else if (c == HID) {
          if (k < HID)            v = W_out[k];
        } else if (c == HID + 1) {
          if (k < HID)            v = W_out[HID + k];
        }
        f[e] = f2bf(v);
      }
      if (t == 0) wf0[kt] = f; else wf1[kt] = f;
    }
  }

  // ---- noise DMA with transposed-swizzle SOURCE: slot tid holds chunk
  // (row = tid&7, chunkcol = tid>>3). Dest stays wave-linear.
  const bool dma = (tid < NCH);
  const float* gsrc = dma
      ? noise + (size_t)(row0 + (tid & 7)) * (SEQ * HID) + ((tid >> 3) << 2)
      : noise;

  __syncthreads();  // Abuf zeros + xbuf visible

  // post-zero init: x_0 into Abuf[0] cols 300-301; bias-one col 302 (both)
  if (tid < 8) {
    float2 xv = *(const float2*)&x[(size_t)(row0 + tid) * (SEQ * 2)];
    *(uint32_t*)&Abuf[0][tid][300] = cvt_pk_bf16(xv.x, xv.y);
    Abuf[0][tid][302] = (short)0x3F80;   // bf16 1.0
    Abuf[1][tid][302] = (short)0x3F80;
  }

  // prologue DMA: slabs 0 and 1
  if (dma) {
    dma16(gsrc, &Nbuf[0][wave * 256]);
    dma16(gsrc + HID, &Nbuf[1][wave * 256]);
  }
  const float* gsrc2 = gsrc + 2 * HID;
  STEP_BARRIER();  // slab 0 landed; slab 1 in flight; init LDS visible

  const bool xw = (wave == 0) && (grp == 0) && lcr;  // lanes 0-7

  // Iteration S: MFMA on Abuf[CUR] (= h_{S-1} + x_S + bias); out[S-1]
  // from cols 300/301 (S>=1); epilogue writes h_S + x_{S+1} (S<SEQ).
#define STEPM(S, CUR, RB, WB, DO_OUT, DO_EPI, DO_X, DO_ADV, DO_DMA)            \
  {                                                                            \
    if (DO_DMA) { if (dma) dma16(gsrc2, &Nbuf[WB][wave * 256]); }              \
    if (DO_ADV) gsrc2 += HID;                                                  \
    const short* Ab = &Abuf[CUR][arow][grp8];                                  \
    /* full A-frag preload: all 10 reads enter the LDS queue up front */       \
    bf16x8 h0 = *(const bf16x8*)(Ab + 0);                                      \
    bf16x8 h1 = *(const bf16x8*)(Ab + 32);                                     \
    bf16x8 h2 = *(const bf16x8*)(Ab + 64);                                     \
    bf16x8 h3 = *(const bf16x8*)(Ab + 96);                                     \
    bf16x8 h4 = *(const bf16x8*)(Ab + 128);                                    \
    bf16x8 h5 = *(const bf16x8*)(Ab + 160);                                    \
    bf16x8 h6 = *(const bf16x8*)(Ab + 192);                                    \
    bf16x8 h7 = *(const bf16x8*)(Ab + 224);                                    \
    bf16x8 h8 = *(const bf16x8*)(Ab + 256);                                    \
    bf16x8 h9 = *(const bf16x8*)(Ab + 288);                                    \
    f32x4 t0a = {0.f,0.f,0.f,0.f}, t0b = {0.f,0.f,0.f,0.f};                    \
    f32x4 t1a = {0.f,0.f,0.f,0.f}, t1b = {0.f,0.f,0.f,0.f};                    \
    t0a = __builtin_amdgcn_mfma_f32_16x16x32_bf16(wf0[0], h0, t0a, 0,0,0);     \
    t1a = __builtin_amdgcn_mfma_f32_16x16x32_bf16(wf1[0], h0, t1a, 0,0,0);     \
    t0b = __builtin_amdgcn_mfma_f32_16x16x32_bf16(wf0[1], h1, t0b, 0,0,0);     \
    t1b = __builtin_amdgcn_mfma_f32_16x16x32_bf16(wf1[1], h1, t1b, 0,0,0);     \
    t0a = __builtin_amdgcn_mfma_f32_16x16x32_bf16(wf0[2], h2, t0a, 0,0,0);     \
    t1a = __builtin_amdgcn_mfma_f32_16x16x32_bf16(wf1[2], h2, t1a, 0,0,0);     \
    t0b = __builtin_amdgcn_mfma_f32_16x16x32_bf16(wf0[3], h3, t0b, 0,0,0);     \
    t1b = __builtin_amdgcn_mfma_f32_16x16x32_bf16(wf1[3], h3, t1b, 0,0,0);     \
    t0a = __builtin_amdgcn_mfma_f32_16x16x32_bf16(wf0[4], h4, t0a, 0,0,0);     \
    t1a = __builtin_amdgcn_mfma_f32_16x16x32_bf16(wf1[4], h4, t1a, 0,0,0);     \
    t0b = __builtin_amdgcn_mfma_f32_16x16x32_bf16(wf0[5], h5, t0b, 0,0,0);     \
    t1b = __builtin_amdgcn_mfma_f32_16x16x32_bf16(wf1[5], h5, t1b, 0,0,0);     \
    t0a = __builtin_amdgcn_mfma_f32_16x16x32_bf16(wf0[6], h6, t0a, 0,0,0);     \
    t1a = __builtin_amdgcn_mfma_f32_16x16x32_bf16(wf1[6], h6, t1a, 0,0,0);     \
    t0b = __builtin_amdgcn_mfma_f32_16x16x32_bf16(wf0[7], h7, t0b, 0,0,0);     \
    t1b = __builtin_amdgcn_mfma_f32_16x16x32_bf16(wf1[7], h7, t1b, 0,0,0);     \
    t0a = __builtin_amdgcn_mfma_f32_16x16x32_bf16(wf0[8], h8, t0a, 0,0,0);     \
    t1a = __builtin_amdgcn_mfma_f32_16x16x32_bf16(wf1[8], h8, t1a, 0,0,0);     \
    t0b = __builtin_amdgcn_mfma_f32_16x16x32_bf16(wf0[9], h9, t0b, 0,0,0);     \
    t1b = __builtin_amdgcn_mfma_f32_16x16x32_bf16(wf1[9], h9, t1b, 0,0,0);     \
    f32x4 ac0 = t0a + t0b, ac1 = t1a + t1b;                                    \
    if (w9) {                                                                  \
      if (DO_OUT) { if (grp == 3 && lcr) {                                     \
        float2 o; o.x = ac0[0] + bout0; o.y = ac0[1] + bout1;                  \
        *(float2*)&outbuf[lc][((S) - 1) * 2] = o;                              \
      } }                                                                      \
      if (DO_EPI) { if (lcr && grp < 3) {                                      \
        float4 nz = *(const float4*)&Nbuf[RB][nb0];                            \
        float h0v = fmaxf(ac0[0], 0.f) + 0.01f * nz.x;                         \
        float h1v = fmaxf(ac0[1], 0.f) + 0.01f * nz.y;                         \
        float h2v = fmaxf(ac0[2], 0.f) + 0.01f * nz.z;                         \
        float h3v = fmaxf(ac0[3], 0.f) + 0.01f * nz.w;                         \
        uint2 pk; pk.x = cvt_pk_bf16(h0v, h1v); pk.y = cvt_pk_bf16(h2v, h3v);  \
        *(uint2*)&Abuf[(CUR) ^ 1][lc][cb0] = pk;                               \
      } }                                                                      \
    } else {                                                                   \
      if (DO_EPI) { if (lcr) {                                                 \
        float4 nz0 = *(const float4*)&Nbuf[RB][nb0];                           \
        float4 nz1 = *(const float4*)&Nbuf[RB][nb0 + 128];                     \
        float a0 = fmaxf(ac0[0], 0.f) + 0.01f * nz0.x;                         \
        float a1 = fmaxf(ac0[1], 0.f) + 0.01f * nz0.y;                         \
        float a2 = fmaxf(ac0[2], 0.f) + 0.01f * nz0.z;                         \
        float a3 = fmaxf(ac0[3], 0.f) + 0.01f * nz0.w;                         \
        float b0 = fmaxf(ac1[0], 0.f) + 0.01f * nz1.x;                         \
        float b1 = fmaxf(ac1[1], 0.f) + 0.01f * nz1.y;                         \
        float b2 = fmaxf(ac1[2], 0.f) + 0.01f * nz1.z;                         \
        float b3 = fmaxf(ac1[3], 0.f) + 0.01f * nz1.w;                         \
        uint2 p0; p0.x = cvt_pk_bf16(a0, a1); p0.y = cvt_pk_bf16(a2, a3);      \
        uint2 p1; p1.x = cvt_pk_bf16(b0, b1); p1.y = cvt_pk_bf16(b2, b3);      \
        *(uint2*)&Abuf[(CUR) ^ 1][lc][cb0] = p0;                               \
        *(uint2*)&Abuf[(CUR) ^ 1][lc][cb0 + 16] = p1;                          \
      } }                                                                      \
    }                                                                          \
    if (DO_X) { if (xw) {                                                      \
      float2 xv = *(const float2*)&xbuf[lc][((S) + 1) * 2];                    \
      *(uint32_t*)&Abuf[(CUR) ^ 1][lc][300] = cvt_pk_bf16(xv.x, xv.y);         \
    } }                                                                        \
    if (DO_EPI) STEP_BARRIER();                                                \
  }

  // peeled first block (S=0..5): no out-write at S=0
  STEPM(0, 0, 0, 2, 0, 1, 1, 1, 1);
  STEPM(1, 1, 1, 0, 1, 1, 1, 1, 1);
  STEPM(2, 0, 2, 1, 1, 1, 1, 1, 1);
  STEPM(3, 1, 0, 2, 1, 1, 1, 1, 1);
  STEPM(4, 0, 1, 0, 1, 1, 1, 1, 1);
  STEPM(5, 1, 2, 1, 1, 1, 1, 1, 1);

  // main: S = 6..119 (19 blocks of 6; all guards statically true)
  for (int s = 6; s < 120; s += 6) {
    STEPM(s + 0, 0, 0, 2, 1, 1, 1, 1, 1);
    STEPM(s + 1, 1, 1, 0, 1, 1, 1, 1, 1);
    STEPM(s + 2, 0, 2, 1, 1, 1, 1, 1, 1);
    STEPM(s + 3, 1, 0, 2, 1, 1, 1, 1, 1);
    STEPM(s + 4, 0, 1, 0, 1, 1, 1, 1, 1);
    STEPM(s + 5, 1, 2, 1, 1, 1, 1, 1, 1);
  }

  // tail S=120..125 (static guards; slab-124 re-issues keep vmcnt uniform)
  STEPM(120, 0, 0, 2, 1, 1, 1, 1, 1);
  STEPM(121, 1, 1, 0, 1, 1, 1, 1, 1);
  STEPM(122, 0, 2, 1, 1, 1, 1, 0, 1);  // no more advance (slab 124 is last)
  STEPM(123, 1, 0, 2, 1, 1, 1, 0, 1);
  STEPM(124, 0, 1, 0, 1, 1, 0, 0, 1);  // no x_125
  STEPM(125, 1, 2, 1, 1, 0, 0, 0, 0);  // MFMA + out[124] only, no barrier

#undef STEPM

  __syncthreads();  // full drain; outbuf visible

  // coalesced flush
  for (int i = tid; i < RPW * SEQ * 2; i += NTH) {
    int r = i / (SEQ * 2), j = i % (SEQ * 2);
    out[(row0 + r) * (SEQ * 2) + j] = outbuf[r][j];
  }
}

extern "C" void kernel_launch(void* const* d_in, const int* in_sizes, int n_in,
                              void* d_out, int out_size, void* d_ws, size_t ws_size,
                              hipStream_t stream) {
  const float* xp     = (const float*)d_in[0];
  const float* noise  = (const float*)d_in[1];
  const float* W_ih   = (const float*)d_in[2];
  const float* b_ih   = (const float*)d_in[3];
  const float* W_hh   = (const float*)d_in[4];
  const float* b_hh   = (const float*)d_in[5];
  const float* W_out  = (const float*)d_in[6];
  const float* b_out  = (const float*)d_in[7];
  float* outp         = (float*)d_out;

  rnn_fused<<<dim3(2048 / RPW), dim3(NTH), 0, stream>>>(
      xp, noise, W_ih, b_ih, W_hh, b_hh, W_out, b_out, outp);
}